// Round 11
// baseline (2364.064 us; speedup 1.0000x reference)
//
#include <hip/hip_runtime.h>
#include <hip/hip_bf16.h>
#include <cstdint>
#include <cstddef>

typedef __hip_bfloat16 bf16;
typedef short bf16x8 __attribute__((ext_vector_type(8)));   // 8 bf16 (4 VGPRs)
typedef float f32x4 __attribute__((ext_vector_type(4)));

#define SQRT_E   27.712812921102035f   // sqrt(768)
#define ASCALE   (0.05f * 27.712812921102035f)
#define MPAD     3200                  // 3152 tokens padded to 25 * 128

__device__ __forceinline__ void load_lds16(const bf16* g, bf16* l) {
    __builtin_amdgcn_global_load_lds(
        (const __attribute__((address_space(1))) void*)g,
        (__attribute__((address_space(3))) void*)l, 16, 0, 0);
}

__device__ __forceinline__ float block_sum(float v, float* sbuf) {
#pragma unroll
    for (int m = 32; m >= 1; m >>= 1) v += __shfl_xor(v, m);
    __syncthreads();
    if ((threadIdx.x & 63) == 0) sbuf[threadIdx.x >> 6] = v;
    __syncthreads();
    return sbuf[0] + sbuf[1] + sbuf[2] + sbuf[3];
}

__device__ __forceinline__ void cvt8(const float* s, bf16* d) {
    float4 f0 = *(const float4*)s;
    float4 f1 = *(const float4*)(s + 4);
    bf16 t[8];
    t[0] = __float2bfloat16(f0.x); t[1] = __float2bfloat16(f0.y);
    t[2] = __float2bfloat16(f0.z); t[3] = __float2bfloat16(f0.w);
    t[4] = __float2bfloat16(f1.x); t[5] = __float2bfloat16(f1.y);
    t[6] = __float2bfloat16(f1.z); t[7] = __float2bfloat16(f1.w);
    *reinterpret_cast<uint4*>(d) = *reinterpret_cast<const uint4*>(t);
}

// wconv body: converts one layer's 7 weight mats (1179648 groups of 8 f32)
__device__ __forceinline__ void wconv_body(
    int idx,
    const float* __restrict__ wq, const float* __restrict__ wk,
    const float* __restrict__ wv, const float* __restrict__ wo,
    const float* __restrict__ wu, const float* __restrict__ wg,
    const float* __restrict__ wd, bf16* __restrict__ dst) {
    const float* src;
    size_t off;
    if (idx < 294912) {
        int seg = idx / 73728, o = idx - seg * 73728;
        src = (seg == 0) ? wq : (seg == 1) ? wk : (seg == 2) ? wv : wo;
        off = (size_t)o * 8;
    } else {
        int i2 = idx - 294912;
        int seg = i2 / 294912, o = i2 - seg * 294912;
        src = (seg == 0) ? wu : (seg == 1) ? wg : wd;
        off = (size_t)o * 8;
    }
    cvt8(src + off, dst + (size_t)idx * 8);
}

// ---------------- pre-loop stage 1: patchw cvt + im2col -----------------------
// blocks [0,288): patchw f32->bf16; blocks [288,9888): im2col
__global__ __launch_bounds__(256) void prep_kernel(
    const float* __restrict__ x, bf16* __restrict__ A,
    const float* __restrict__ patchw, bf16* __restrict__ pwb) {
    int b = blockIdx.x, tid = threadIdx.x;
    if (b < 288) {
        int idx = b * 256 + tid;                 // < 73728 exactly
        cvt8(patchw + (size_t)idx * 8, pwb + (size_t)idx * 8);
    } else {
        int idx = (b - 288) * 256 + tid;         // < 2457600 exactly
        int row = idx / 768, col = idx - row * 768;
        if (row >= 3136) { A[idx] = __float2bfloat16(0.f); return; }
        int bb = row / 196, pp = row - bb * 196;
        int gy = pp / 14, gx = pp - gy * 14;
        int c = col >> 8, rem = col & 255, py = rem >> 4, px = rem & 15;
        A[idx] = __float2bfloat16(
            x[((size_t)(bb * 3 + c) * 224 + gy * 16 + py) * 224 + gx * 16 + px]);
    }
}

// ---------------- pre-loop stage 2: patch GEMM + assemble + cls + wconv0 ------
// blocks [0,150): patch-embed GEMM 128x128 tiles, epilogue adds pb+pos and
//                 writes h/hb directly (assemble fused; tokens n>=1)
// blocks [150,166): cls rows (token 0 of each batch)
// blocks [166,4774): layer-0 wconv -> wdst (fills CUs idle during the GEMM)
__global__ __launch_bounds__(256) void patch_fused(
    const bf16* __restrict__ A, const bf16* __restrict__ Bw,
    const float* __restrict__ pb, const float* __restrict__ cls,
    const float* __restrict__ pos,
    float* __restrict__ h, bf16* __restrict__ hb,
    const float* __restrict__ wq, const float* __restrict__ wk,
    const float* __restrict__ wv, const float* __restrict__ wo,
    const float* __restrict__ wu, const float* __restrict__ wg,
    const float* __restrict__ wd, bf16* __restrict__ wdst) {
    __shared__ __align__(16) bf16 As[128 * 32];
    __shared__ __align__(16) bf16 Bs[128 * 32];
    const int bb = blockIdx.x;
    const int tid = threadIdx.x;
    if (bb >= 166) {
        int idx = (bb - 166) * 256 + tid;        // < 1179648 exactly
        wconv_body(idx, wq, wk, wv, wo, wu, wg, wd, wdst);
        return;
    }
    if (bb >= 150) {
        int bi = bb - 150;                       // batch 0..15
        size_t row = (size_t)bi * 197 * 768;
#pragma unroll
        for (int i = 0; i < 3; i++) {
            int c = tid + i * 256;
            float v = cls[c] + pos[c];
            h[row + c] = v;
            hb[row + c] = __float2bfloat16(v);
        }
        return;
    }
    const int lane = tid & 63, wave = tid >> 6;
    const int wm = wave & 1, wn = wave >> 1;
    const int quad = lane >> 4, l16 = lane & 15;
    const int nt = bb % 6;
    const int row0 = (bb / 6) * 128;
    const int col0 = nt * 128;
    const bf16* Ab = A + (size_t)row0 * 768;
    const bf16* Bb = Bw + (size_t)col0 * 768;

    f32x4 acc[4][4];
    f32x4 zero = {0.f, 0.f, 0.f, 0.f};
#pragma unroll
    for (int i = 0; i < 4; i++)
#pragma unroll
        for (int j = 0; j < 4; j++) acc[i][j] = zero;

    for (int k0 = 0; k0 < 768; k0 += 32) {
#pragma unroll
        for (int it = 0; it < 2; ++it) {
            int cidx = it * 256 + tid;
            int r = cidx >> 2, cg = cidx & 3;
            load_lds16(Ab + (size_t)r * 768 + k0 + cg * 8, As + cidx * 8);
            load_lds16(Bb + (size_t)r * 768 + k0 + cg * 8, Bs + cidx * 8);
        }
        __syncthreads();
        bf16x8 av[4], bv[4];
#pragma unroll
        for (int i = 0; i < 4; i++) {
            av[i] = *(const bf16x8*)(As + (wm * 64 + i * 16 + l16) * 32 + quad * 8);
            bv[i] = *(const bf16x8*)(Bs + (wn * 64 + i * 16 + l16) * 32 + quad * 8);
        }
#pragma unroll
        for (int i = 0; i < 4; i++)
#pragma unroll
            for (int j = 0; j < 4; j++)
                acc[i][j] = __builtin_amdgcn_mfma_f32_16x16x32_bf16(av[i], bv[j], acc[i][j], 0, 0, 0);
        __syncthreads();
    }
    // fused assemble: tproj + pb + pos -> h, hb (tokens n>=1)
#pragma unroll
    for (int i = 0; i < 4; i++) {
        int rr = row0 + wm * 64 + i * 16 + quad * 4;
#pragma unroll
        for (int j = 0; j < 4; j++) {
            int cc = col0 + wn * 64 + j * 16 + l16;
#pragma unroll
            for (int r = 0; r < 4; r++) {
                int p = rr + r;                  // patch row 0..3199
                if (p < 3136) {
                    int bi = p / 196, n = p - bi * 196;
                    float val = acc[i][j][r] + pb[cc] + pos[(size_t)(n + 1) * 768 + cc];
                    size_t hr = (size_t)(bi * 197 + n + 1) * 768 + cc;
                    h[hr] = val;
                    hb[hr] = __float2bfloat16(val);
                }
            }
        }
    }
}

// ---------------- bf16 GEMM: C = A @ W^T (m97 structure, all-bf16 staging) ----
// grid.x = nSegs*tilesPerSeg; grid.y = M/128; grid.z = split-K part
__global__ __launch_bounds__(256) void gemm_bt(
    const bf16* __restrict__ A, int lda,
    const bf16* __restrict__ B0, const bf16* __restrict__ B1, const bf16* __restrict__ B2,
    int tilesPerSeg, int segColStride,
    void* __restrict__ Cv, int ldc, long long partStride,
    int Klen, int ldb, int outBf16) {
    __shared__ __align__(16) bf16 As[128 * 32];
    __shared__ __align__(16) bf16 Bs[128 * 32];
    const int tid = threadIdx.x;
    const int lane = tid & 63, wave = tid >> 6;
    const int wm = wave & 1, wn = wave >> 1;
    const int quad = lane >> 4, l16 = lane & 15;
    const int seg = blockIdx.x / tilesPerSeg;
    const int nt = blockIdx.x - seg * tilesPerSeg;
    const bf16* B = (seg == 0) ? B0 : (seg == 1 ? B1 : B2);
    const int row0 = blockIdx.y * 128;
    const int col0 = nt * 128;
    const long long kofs = (long long)blockIdx.z * Klen;
    const bf16* Ab = A + (size_t)row0 * lda + kofs;
    const bf16* Bb = B + (size_t)col0 * ldb + kofs;
    const long long cofs = (long long)blockIdx.z * partStride + (long long)seg * segColStride;

    f32x4 acc[4][4];
    f32x4 zero = {0.f, 0.f, 0.f, 0.f};
#pragma unroll
    for (int i = 0; i < 4; i++)
#pragma unroll
        for (int j = 0; j < 4; j++) acc[i][j] = zero;

    for (int k0 = 0; k0 < Klen; k0 += 32) {
#pragma unroll
        for (int it = 0; it < 2; ++it) {
            int cidx = it * 256 + tid;
            int r = cidx >> 2, cg = cidx & 3;
            load_lds16(Ab + (size_t)r * lda + k0 + cg * 8, As + cidx * 8);
            load_lds16(Bb + (size_t)r * ldb + k0 + cg * 8, Bs + cidx * 8);
        }
        __syncthreads();
        bf16x8 av[4], bv[4];
#pragma unroll
        for (int i = 0; i < 4; i++) {
            av[i] = *(const bf16x8*)(As + (wm * 64 + i * 16 + l16) * 32 + quad * 8);
            bv[i] = *(const bf16x8*)(Bs + (wn * 64 + i * 16 + l16) * 32 + quad * 8);
        }
#pragma unroll
        for (int i = 0; i < 4; i++)
#pragma unroll
            for (int j = 0; j < 4; j++)
                acc[i][j] = __builtin_amdgcn_mfma_f32_16x16x32_bf16(av[i], bv[j], acc[i][j], 0, 0, 0);
        __syncthreads();
    }
    if (outBf16) {
        bf16* Cb = (bf16*)Cv + cofs;
#pragma unroll
        for (int i = 0; i < 4; i++) {
            int rr = row0 + wm * 64 + i * 16 + quad * 4;
#pragma unroll
            for (int j = 0; j < 4; j++) {
                int cc = col0 + wn * 64 + j * 16 + l16;
#pragma unroll
                for (int r = 0; r < 4; r++)
                    Cb[(size_t)(rr + r) * ldc + cc] = __float2bfloat16(acc[i][j][r]);
            }
        }
    } else {
        float* Cb = (float*)Cv + cofs;
#pragma unroll
        for (int i = 0; i < 4; i++) {
            int rr = row0 + wm * 64 + i * 16 + quad * 4;
#pragma unroll
            for (int j = 0; j < 4; j++) {
                int cc = col0 + wn * 64 + j * 16 + l16;
#pragma unroll
                for (int r = 0; r < 4; r++)
                    Cb[(size_t)(rr + r) * ldc + cc] = acc[i][j][r];
            }
        }
    }
}

// ---------------- fused QKV GEMM + q/k cosine-norm + next-layer wconv ---------
// blocks [0,450): QKV GEMM (seg = b/150 in {q,k,v}; rem = b%150: nt = rem%6,
//                 ry = rem/6). Each wave's 64-col span is one complete head.
// blocks [450,5058): f32->bf16 conversion of layer l+1 weights -> wdst
__global__ __launch_bounds__(256) void gemm_qkv(
    const bf16* __restrict__ A,
    const bf16* __restrict__ Bq, const bf16* __restrict__ Bk, const bf16* __restrict__ Bv,
    const float* __restrict__ s_l,
    bf16* __restrict__ Qd, bf16* __restrict__ Kd, bf16* __restrict__ VTd,
    const float* __restrict__ wq, const float* __restrict__ wk,
    const float* __restrict__ wv, const float* __restrict__ wo,
    const float* __restrict__ wu, const float* __restrict__ wg,
    const float* __restrict__ wd, bf16* __restrict__ wdst) {
    __shared__ __align__(16) bf16 As[128 * 32];
    __shared__ __align__(16) bf16 Bs[128 * 32];
    const int bb = blockIdx.x;
    const int tid = threadIdx.x;
    if (bb >= 450) {
        int idx = (bb - 450) * 256 + tid;        // < 1179648 exactly
        wconv_body(idx, wq, wk, wv, wo, wu, wg, wd, wdst);
        return;
    }
    const int lane = tid & 63, wave = tid >> 6;
    const int wm = wave & 1, wn = wave >> 1;
    const int quad = lane >> 4, l16 = lane & 15;
    const int seg = bb / 150;
    const int rem = bb - seg * 150;
    const int nt = rem % 6;
    const int row0 = (rem / 6) * 128;
    const int col0 = nt * 128;
    const bf16* B = (seg == 0) ? Bq : (seg == 1 ? Bk : Bv);
    const bf16* Ab = A + (size_t)row0 * 768;
    const bf16* Bb = B + (size_t)col0 * 768;

    f32x4 acc[4][4];
    f32x4 zero = {0.f, 0.f, 0.f, 0.f};
#pragma unroll
    for (int i = 0; i < 4; i++)
#pragma unroll
        for (int j = 0; j < 4; j++) acc[i][j] = zero;

    for (int k0 = 0; k0 < 768; k0 += 32) {
#pragma unroll
        for (int it = 0; it < 2; ++it) {
            int cidx = it * 256 + tid;
            int r = cidx >> 2, cg = cidx & 3;
            load_lds16(Ab + (size_t)r * 768 + k0 + cg * 8, As + cidx * 8);
            load_lds16(Bb + (size_t)r * 768 + k0 + cg * 8, Bs + cidx * 8);
        }
        __syncthreads();
        bf16x8 av[4], bv[4];
#pragma unroll
        for (int i = 0; i < 4; i++) {
            av[i] = *(const bf16x8*)(As + (wm * 64 + i * 16 + l16) * 32 + quad * 8);
            bv[i] = *(const bf16x8*)(Bs + (wn * 64 + i * 16 + l16) * 32 + quad * 8);
        }
#pragma unroll
        for (int i = 0; i < 4; i++)
#pragma unroll
            for (int j = 0; j < 4; j++)
                acc[i][j] = __builtin_amdgcn_mfma_f32_16x16x32_bf16(av[i], bv[j], acc[i][j], 0, 0, 0);
        __syncthreads();
    }

    const int hcol = nt * 2 + wn;               // complete head owned by this wave
    if (seg < 2) {
        bf16* Dst = (seg == 0) ? Qd : Kd;
        float sv0[4];
#pragma unroll
        for (int j = 0; j < 4; j++) sv0[j] = s_l[hcol * 64 + j * 16 + l16] * SQRT_E;
#pragma unroll
        for (int i = 0; i < 4; i++) {
#pragma unroll
            for (int r = 0; r < 4; r++) {
                float ss = acc[i][0][r] * acc[i][0][r] + acc[i][1][r] * acc[i][1][r]
                         + acc[i][2][r] * acc[i][2][r] + acc[i][3][r] * acc[i][3][r];
#pragma unroll
                for (int m = 1; m < 16; m <<= 1) ss += __shfl_xor(ss, m);
                float inv = 1.f / fmaxf(sqrtf(ss), 1e-6f);
                int t = row0 + wm * 64 + i * 16 + quad * 4 + r;
                if (t < 3152) {
                    int b = t / 197, n = t - b * 197;
                    size_t base = ((size_t)(b * 12 + hcol) * 208 + n) * 64;
#pragma unroll
                    for (int j = 0; j < 4; j++)
                        Dst[base + j * 16 + l16] =
                            __float2bfloat16(acc[i][j][r] * inv * sv0[j]);
                }
            }
        }
    } else {
#pragma unroll
        for (int i = 0; i < 4; i++) {
#pragma unroll
            for (int r = 0; r < 4; r++) {
                int t = row0 + wm * 64 + i * 16 + quad * 4 + r;
                if (t < 3152) {
                    int b = t / 197, n = t - b * 197;
                    size_t vbase = (size_t)(b * 12 + hcol) * 64 * 224 + n;
#pragma unroll
                    for (int j = 0; j < 4; j++)
                        VTd[vbase + (size_t)(j * 16 + l16) * 224] =
                            __float2bfloat16(acc[i][j][r]);
                }
            }
        }
    }
}

// ---------------- fused up/gate GEMM + SwiGLU -> hidden bf16 ------------------
__global__ __launch_bounds__(256) void gemm_upgate(
    const bf16* __restrict__ A, const bf16* __restrict__ Bu, const bf16* __restrict__ Bv,
    const float* __restrict__ su, const float* __restrict__ sv,
    bf16* __restrict__ H) {
    __shared__ __align__(16) bf16 As[128 * 32];
    __shared__ __align__(16) bf16 Bus[64 * 32];
    __shared__ __align__(16) bf16 Bvs[64 * 32];
    const int tid = threadIdx.x;
    const int lane = tid & 63, wave = tid >> 6;
    const int wm = wave & 1, wn = wave >> 1;     // wn in 0..1 -> 32-col half
    const int quad = lane >> 4, l16 = lane & 15;
    const int ct = blockIdx.x;                   // 0..47
    const int row0 = blockIdx.y * 128;
    const bf16* Ab = A + (size_t)row0 * 768;
    const bf16* Bub = Bu + (size_t)ct * 64 * 768;
    const bf16* Bvb = Bv + (size_t)ct * 64 * 768;

    f32x4 au[4][2], av_[4][2];
    f32x4 zero = {0.f, 0.f, 0.f, 0.f};
#pragma unroll
    for (int i = 0; i < 4; i++)
#pragma unroll
        for (int j = 0; j < 2; j++) { au[i][j] = zero; av_[i][j] = zero; }

    for (int k0 = 0; k0 < 768; k0 += 32) {
#pragma unroll
        for (int it = 0; it < 2; ++it) {
            int cidx = it * 256 + tid;
            int r = cidx >> 2, cg = cidx & 3;
            load_lds16(Ab + (size_t)r * 768 + k0 + cg * 8, As + cidx * 8);
        }
        {
            int r = tid >> 2, cg = tid & 3;
            load_lds16(Bub + (size_t)r * 768 + k0 + cg * 8, Bus + tid * 8);
            load_lds16(Bvb + (size_t)r * 768 + k0 + cg * 8, Bvs + tid * 8);
        }
        __syncthreads();
        bf16x8 a[4], bu[2], bv[2];
#pragma unroll
        for (int i = 0; i < 4; i++)
            a[i] = *(const bf16x8*)(As + (wm * 64 + i * 16 + l16) * 32 + quad * 8);
#pragma unroll
        for (int j = 0; j < 2; j++) {
            bu[j] = *(const bf16x8*)(Bus + (wn * 32 + j * 16 + l16) * 32 + quad * 8);
            bv[j] = *(const bf16x8*)(Bvs + (wn * 32 + j * 16 + l16) * 32 + quad * 8);
        }
#pragma unroll
        for (int i = 0; i < 4; i++)
#pragma unroll
            for (int j = 0; j < 2; j++) {
                au[i][j]  = __builtin_amdgcn_mfma_f32_16x16x32_bf16(a[i], bu[j], au[i][j], 0, 0, 0);
                av_[i][j] = __builtin_amdgcn_mfma_f32_16x16x32_bf16(a[i], bv[j], av_[i][j], 0, 0, 0);
            }
        __syncthreads();
    }
#pragma unroll
    for (int j = 0; j < 2; j++) {
        int cc = ct * 64 + wn * 32 + j * 16 + l16;
        float suc = su[cc];
        float svc = sv[cc] * SQRT_E;
#pragma unroll
        for (int i = 0; i < 4; i++) {
            int rr = row0 + wm * 64 + i * 16 + quad * 4;
#pragma unroll
            for (int r = 0; r < 4; r++) {
                float u = au[i][j][r] * suc;
                float v = av_[i][j][r] * svc;
                float sig = 1.f / (1.f + __expf(-v));
                H[(size_t)(rr + r) * 3072 + cc] = __float2bfloat16(u * v * sig);
            }
        }
    }
}

// ---------------- attention: one wave per (b,h, q-tile PAIR) ------------------
// Two q-tiles per wave: K fragments loaded once feed both QK^T accumulators;
// V fragments shared between both PV MFMAs (halves K/V global traffic and
// block count). No-max softmax (|logit*8| <= 8); 1/sum folded into epilogue.
// grid: 192 bh x 7 pairs (pair 6 has only q-tile 12).
__global__ __launch_bounds__(64) void attn_kernel(
    const bf16* __restrict__ Q, const bf16* __restrict__ K,
    const bf16* __restrict__ VT, bf16* __restrict__ O) {
    __shared__ __align__(16) bf16 Ps[2][16 * 224];
    int lane = threadIdx.x;
    int quad = lane >> 4, l16 = lane & 15;
    int bh = blockIdx.x % 192;
    int pr = blockIdx.x / 192;                   // 0..6
    int qt0 = pr * 2;
    bool has2 = (qt0 + 1) < 13;
    int b = bh / 12, h = bh - b * 12;
    const bf16* Qb = Q + (size_t)bh * 208 * 64;
    const bf16* Kb = K + (size_t)bh * 208 * 64;
    const bf16* Vb = VT + (size_t)bh * 64 * 224;
    f32x4 zero = {0.f, 0.f, 0.f, 0.f};

    bf16x8 a00 = *(const bf16x8*)(Qb + (qt0 * 16 + l16) * 64 + quad * 8);
    bf16x8 a01 = *(const bf16x8*)(Qb + (qt0 * 16 + l16) * 64 + quad * 8 + 32);
    bf16x8 a10 = a00, a11 = a01;
    if (has2) {
        a10 = *(const bf16x8*)(Qb + ((qt0 + 1) * 16 + l16) * 64 + quad * 8);
        a11 = *(const bf16x8*)(Qb + ((qt0 + 1) * 16 + l16) * 64 + quad * 8 + 32);
    }

    f32x4 lg0[13], lg1[13];
#pragma unroll
    for (int kt = 0; kt < 13; kt++) {
        bf16x8 b0 = *(const bf16x8*)(Kb + (kt * 16 + l16) * 64 + quad * 8);
        bf16x8 b1 = *(const bf16x8*)(Kb + (kt * 16 + l16) * 64 + quad * 8 + 32);
        f32x4 c = zero;
        c = __builtin_amdgcn_mfma_f32_16x16x32_bf16(a00, b0, c, 0, 0, 0);
        c = __builtin_amdgcn_mfma_f32_16x16x32_bf16(a01, b1, c, 0, 0, 0);
        lg0[kt] = c;
        if (has2) {
            f32x4 d = zero;
            d = __builtin_amdgcn_mfma_f32_16x16x32_bf16(a10, b0, d, 0, 0, 0);
            d = __builtin_amdgcn_mfma_f32_16x16x32_bf16(a11, b1, d, 0, 0, 0);
            lg1[kt] = d;
        }
    }
    float sm0[4] = {0.f, 0.f, 0.f, 0.f}, sm1[4] = {0.f, 0.f, 0.f, 0.f};
#pragma unroll
    for (int kt = 0; kt < 13; kt++) {
        bool valid = (kt * 16 + l16) < 197;
#pragma unroll
        for (int r = 0; r < 4; r++) {
            float p = valid ? __expf(lg0[kt][r] * 8.0f) : 0.f;
            lg0[kt][r] = p;
            sm0[r] += p;
        }
        if (has2) {
#pragma unroll
            for (int r = 0; r < 4; r++) {
                float p = valid ? __expf(lg1[kt][r] * 8.0f) : 0.f;
                lg1[kt][r] = p;
                sm1[r] += p;
            }
        }
    }
#pragma unroll
    for (int m = 1; m < 16; m <<= 1)
#pragma unroll
        for (int r = 0; r < 4; r++) {
            sm0[r] += __shfl_xor(sm0[r], m);
            sm1[r] += __shfl_xor(sm1[r], m);
        }
    float inv0[4], inv1[4];
#pragma unroll
    for (int r = 0; r < 4; r++) {
        inv0[r] = 1.f / sm0[r];
        inv1[r] = 1.f / sm1[r];
    }
#pragma unroll
    for (int kt = 0; kt < 13; kt++)
#pragma unroll
        for (int r = 0; r < 4; r++) {
            Ps[0][(quad * 4 + r) * 224 + kt * 16 + l16] = __float2bfloat16(lg0[kt][r]);
            if (has2)
                Ps[1][(quad * 4 + r) * 224 + kt * 16 + l16] = __float2bfloat16(lg1[kt][r]);
        }
#pragma unroll
    for (int r = 0; r < 4; r++) {
        Ps[0][(quad * 4 + r) * 224 + 208 + l16] = __float2bfloat16(0.f);
        if (has2) Ps[1][(quad * 4 + r) * 224 + 208 + l16] = __float2bfloat16(0.f);
    }
    __syncthreads();
#pragma unroll
    for (int nt = 0; nt < 4; nt++) {
        f32x4 o0 = zero, o1 = zero;
#pragma unroll
        for (int ks = 0; ks < 7; ks++) {
            bf16x8 vb = *(const bf16x8*)(Vb + (nt * 16 + l16) * 224 + ks * 32 + quad * 8);
            bf16x8 pa0 = *(const bf16x8*)(&Ps[0][l16 * 224 + ks * 32 + quad * 8]);
            o0 = __builtin_amdgcn_mfma_f32_16x16x32_bf16(pa0, vb, o0, 0, 0, 0);
            if (has2) {
                bf16x8 pa1 = *(const bf16x8*)(&Ps[1][l16 * 224 + ks * 32 + quad * 8]);
                o1 = __builtin_amdgcn_mfma_f32_16x16x32_bf16(pa1, vb, o1, 0, 0, 0);
            }
        }
#pragma unroll
        for (int r = 0; r < 4; r++) {
            int tok0 = qt0 * 16 + quad * 4 + r;
            if (tok0 < 197)
                O[(size_t)(b * 197 + tok0) * 768 + h * 64 + nt * 16 + l16] =
                    __float2bfloat16(o0[r] * inv0[r]);
            if (has2) {
                int tok1 = tok0 + 16;
                if (tok1 < 197)
                    O[(size_t)(b * 197 + tok1) * 768 + h * 64 + nt * 16 + l16] =
                        __float2bfloat16(o1[r] * inv1[r]);
            }
        }
    }
}

// ---------------- residual + cosine norms (bf16 split-K partials) -------------
// f32 residual stream (h) — bf16 residual failed accuracy in round 10.
// Optional fused output layernorm: after cosine norm, sum(v^2)=1 exactly, so
// var = 1/768 - mean^2 -> only one extra block_sum needed.
__global__ __launch_bounds__(256) void residual_cos(
    const bf16* __restrict__ proj, int nParts, long long partStride,
    const float* __restrict__ alpha,
    float* __restrict__ h, bf16* __restrict__ hb,
    const float* __restrict__ fcw, const float* __restrict__ fcb,
    float* __restrict__ lnout) {
    __shared__ float sbuf[4];
    int row = blockIdx.x, tid = threadIdx.x;
    float p[3];
    float ss = 0.f;
#pragma unroll
    for (int i = 0; i < 3; i++) {
        int c = tid + i * 256;
        float v = 0.f;
        for (int pt = 0; pt < nParts; pt++)
            v += __bfloat162float(proj[(long long)pt * partStride + (size_t)row * 768 + c]);
        p[i] = v;
        ss += v * v;
    }
    ss = block_sum(ss, sbuf);
    float inv1 = 1.f / fmaxf(sqrtf(ss), 1e-6f);
    float ss2 = 0.f;
#pragma unroll
    for (int i = 0; i < 3; i++) {
        int c = tid + i * 256;
        float hv = h[(size_t)row * 768 + c];
        float a = alpha[c] * ASCALE;
        float m = hv + a * (p[i] * inv1 - hv);
        p[i] = m;
        ss2 += m * m;
    }
    ss2 = block_sum(ss2, sbuf);
    float inv2 = 1.f / fmaxf(sqrtf(ss2), 1e-6f);
    float v0 = p[0] * inv2, v1 = p[1] * inv2, v2 = p[2] * inv2;
    {
        int c = tid;
        h[(size_t)row * 768 + c] = v0;
        hb[(size_t)row * 768 + c] = __float2bfloat16(v0);
        h[(size_t)row * 768 + c + 256] = v1;
        hb[(size_t)row * 768 + c + 256] = __float2bfloat16(v1);
        h[(size_t)row * 768 + c + 512] = v2;
        hb[(size_t)row * 768 + c + 512] = __float2bfloat16(v2);
    }
    if (lnout) {
        float s = block_sum(v0 + v1 + v2, sbuf);
        float mean = s * (1.f / 768.f);
        float var = (1.f / 768.f) - mean * mean;
        float invs = 1.f / sqrtf(var + 1e-6f);
        int b = row / 197, n = row - b * 197;
        if (n >= 1) {
            size_t obase = (size_t)(b * 196 + n - 1) * 768;
            lnout[obase + tid]       = (v0 - mean) * invs * fcw[tid] + fcb[tid];
            lnout[obase + tid + 256] = (v1 - mean) * invs * fcw[tid + 256] + fcb[tid + 256];
            lnout[obase + tid + 512] = (v2 - mean) * invs * fcw[tid + 512] + fcb[tid + 512];
        }
    }
}

extern "C" void kernel_launch(void* const* d_in, const int* in_sizes, int n_in,
                              void* d_out, int out_size, void* d_ws, size_t ws_size,
                              hipStream_t stream) {
    (void)in_sizes; (void)n_in; (void)out_size; (void)ws_size;
    const float* x      = (const float*)d_in[0];
    const float* patchw = (const float*)d_in[1];
    const float* patchb = (const float*)d_in[2];
    const float* cls    = (const float*)d_in[3];
    const float* pos    = (const float*)d_in[4];
    const float* Wq     = (const float*)d_in[5];
    const float* Wk     = (const float*)d_in[6];
    const float* Wv     = (const float*)d_in[7];
    const float* Wo     = (const float*)d_in[8];
    const float* s_qk   = (const float*)d_in[9];
    const float* Wup    = (const float*)d_in[10];
    const float* Wgate  = (const float*)d_in[11];
    const float* Wdown  = (const float*)d_in[12];
    const float* s_u    = (const float*)d_in[13];
    const float* s_v    = (const float*)d_in[14];
    const float* alA    = (const float*)d_in[15];
    const float* alM    = (const float*)d_in[16];
    const float* fcw    = (const float*)d_in[17];
    const float* fcb    = (const float*)d_in[18];
    float* out = (float*)d_out;

    char* ws = (char*)d_ws;
    size_t ofs = 0;
    auto alloc = [&](size_t bytes) -> void* {
        void* p = ws + ofs;
        ofs += (bytes + 255) & ~(size_t)255;
        return p;
    };
    float* h      = (float*)alloc((size_t)MPAD * 768 * 4);        //  9.8 MB (f32 residual)
    float* part   = (float*)alloc((size_t)4 * MPAD * 768 * 4);    // 39.3 MB: bf16 partials | f32 tproj
    bf16*  hb     = (bf16*)alloc((size_t)MPAD * 768 * 2);         //  4.9 MB
    bf16*  attno  = (bf16*)alloc((size_t)MPAD * 768 * 2);         //  4.9 MB
    bf16*  hidden = (bf16*)alloc((size_t)MPAD * 3072 * 2);        // 19.7 MB (also Apatch)
    size_t qkvt_bytes = ((size_t)192 * 208 * 64 * 2) * 2 + (size_t)192 * 64 * 224 * 2;
    bf16*  Qb     = (bf16*)alloc(qkvt_bytes);                     // 15.7 MB
    bf16*  Kb     = Qb + (size_t)192 * 208 * 64;
    bf16*  VTb    = Kb + (size_t)192 * 208 * 64;
    const size_t WPL = 9437184;                                   // bf16 elems per layer
    bf16*  wbf0   = (bf16*)alloc(WPL * 2);                        // 18.9 MB (even layers)
    bf16*  wbf1   = (bf16*)alloc(WPL * 2);                        // 18.9 MB (odd layers)
    bf16*  pwb    = (bf16*)alloc((size_t)589824 * 2);             //  1.2 MB patch weights

    bf16*  partb  = (bf16*)part;                 // in-loop bf16 split-K partials
    bf16*  Apatch = hidden;

    const long long PSTR = (long long)MPAD * 768;
    const size_t EE = 768 * 768, FE = (size_t)3072 * 768;

    // ---- pre-loop: im2col/patchw cvt, then GEMM+assemble+cls+wconv0 fused ----
    prep_kernel<<<9888, 256, 0, stream>>>(x, Apatch, patchw, pwb);
    patch_fused<<<4774, 256, 0, stream>>>(Apatch, pwb, patchb, cls, pos, h, hb,
                                          Wq, Wk, Wv, Wo, Wup, Wgate, Wdown, wbf0);
    // zero Q/K/VT pads once per call (epilogues write only real tokens)
    hipMemsetAsync(Qb, 0, qkvt_bytes, stream);

    for (int l = 0; l < 12; l++) {
        bf16* wl    = (l & 1) ? wbf1 : wbf0;
        bf16* wnext = (l & 1) ? wbf0 : wbf1;
        bf16* wqb = wl;
        bf16* wkb = wl + 589824;
        bf16* wvb = wl + 1179648;
        bf16* wob = wl + 1769472;
        bf16* wub = wl + 2359296;
        bf16* wgb = wl + 4718592;
        bf16* wdb = wl + 7077888;
        int ln = (l < 11) ? (l + 1) : l;         // next-layer weights (unused at l=11)

        // fused QKV GEMM + q/k cosine-norm + overlapped next-layer wconv
        gemm_qkv<<<(l < 11) ? 5058 : 450, 256, 0, stream>>>(
            hb, wqb, wkb, wvb, s_qk + (size_t)l * 768, Qb, Kb, VTb,
            Wq + (size_t)ln * EE, Wk + (size_t)ln * EE,
            Wv + (size_t)ln * EE, Wo + (size_t)ln * EE,
            Wup + (size_t)ln * FE, Wgate + (size_t)ln * FE,
            Wdown + (size_t)ln * FE, wnext);
        attn_kernel<<<1344, 64, 0, stream>>>(Qb, Kb, VTb, attno);
        // O-proj split-K=3 GEMM, bf16 partials (8 K-steps/block, 450 blocks)
        gemm_bt<<<dim3(6, 25, 3), 256, 0, stream>>>(attno, 768, wob, wob, wob,
                                                    6, 0, partb, 768, PSTR, 256, 768, 1);
        residual_cos<<<3152, 256, 0, stream>>>(partb, 3, PSTR, alA + (size_t)l * 768,
                                               h, hb, fcw, fcb, (float*)nullptr);
        // fused up/gate + SwiGLU -> hidden bf16
        gemm_upgate<<<dim3(48, 25), 256, 0, stream>>>(hb, wub, wgb,
                                                      s_u + (size_t)l * 3072,
                                                      s_v + (size_t)l * 3072, hidden);
        // down, split-K = 4, bf16 partials
        gemm_bt<<<dim3(6, 25, 4), 256, 0, stream>>>(hidden, 3072, wdb, wdb, wdb,
                                                    6, 0, partb, 768, PSTR, 768, 3072, 1);
        float* lnp = (l == 10) ? out : (l == 11) ? (out + 2408448) : (float*)nullptr;
        residual_cos<<<3152, 256, 0, stream>>>(partb, 4, PSTR, alM + (size_t)l * 768,
                                               h, hb, fcw, fcb, lnp);
    }
}

// Round 12
// 2316.641 us; speedup vs baseline: 1.0205x; 1.0205x over previous
//
#include <hip/hip_runtime.h>
#include <hip/hip_bf16.h>
#include <cstdint>
#include <cstddef>

typedef __hip_bfloat16 bf16;
typedef short bf16x8 __attribute__((ext_vector_type(8)));   // 8 bf16 (4 VGPRs)
typedef float f32x4 __attribute__((ext_vector_type(4)));

#define SQRT_E   27.712812921102035f   // sqrt(768)
#define ASCALE   (0.05f * 27.712812921102035f)
#define MPAD     3200                  // 3152 tokens padded to 25 * 128

__device__ __forceinline__ void load_lds16(const bf16* g, bf16* l) {
    __builtin_amdgcn_global_load_lds(
        (const __attribute__((address_space(1))) void*)g,
        (__attribute__((address_space(3))) void*)l, 16, 0, 0);
}

__device__ __forceinline__ float block_sum(float v, float* sbuf) {
#pragma unroll
    for (int m = 32; m >= 1; m >>= 1) v += __shfl_xor(v, m);
    __syncthreads();
    if ((threadIdx.x & 63) == 0) sbuf[threadIdx.x >> 6] = v;
    __syncthreads();
    return sbuf[0] + sbuf[1] + sbuf[2] + sbuf[3];
}

__device__ __forceinline__ void cvt8(const float* s, bf16* d) {
    float4 f0 = *(const float4*)s;
    float4 f1 = *(const float4*)(s + 4);
    bf16 t[8];
    t[0] = __float2bfloat16(f0.x); t[1] = __float2bfloat16(f0.y);
    t[2] = __float2bfloat16(f0.z); t[3] = __float2bfloat16(f0.w);
    t[4] = __float2bfloat16(f1.x); t[5] = __float2bfloat16(f1.y);
    t[6] = __float2bfloat16(f1.z); t[7] = __float2bfloat16(f1.w);
    *reinterpret_cast<uint4*>(d) = *reinterpret_cast<const uint4*>(t);
}

// wconv body: converts one layer's 7 weight mats (1179648 groups of 8 f32)
__device__ __forceinline__ void wconv_body(
    int idx,
    const float* __restrict__ wq, const float* __restrict__ wk,
    const float* __restrict__ wv, const float* __restrict__ wo,
    const float* __restrict__ wu, const float* __restrict__ wg,
    const float* __restrict__ wd, bf16* __restrict__ dst) {
    const float* src;
    size_t off;
    if (idx < 294912) {
        int seg = idx / 73728, o = idx - seg * 73728;
        src = (seg == 0) ? wq : (seg == 1) ? wk : (seg == 2) ? wv : wo;
        off = (size_t)o * 8;
    } else {
        int i2 = idx - 294912;
        int seg = i2 / 294912, o = i2 - seg * 294912;
        src = (seg == 0) ? wu : (seg == 1) ? wg : wd;
        off = (size_t)o * 8;
    }
    cvt8(src + off, dst + (size_t)idx * 8);
}

// ---------------- pre-loop stage 1: patchw cvt + im2col -----------------------
// blocks [0,288): patchw f32->bf16; blocks [288,9888): im2col
__global__ __launch_bounds__(256) void prep_kernel(
    const float* __restrict__ x, bf16* __restrict__ A,
    const float* __restrict__ patchw, bf16* __restrict__ pwb) {
    int b = blockIdx.x, tid = threadIdx.x;
    if (b < 288) {
        int idx = b * 256 + tid;                 // < 73728 exactly
        cvt8(patchw + (size_t)idx * 8, pwb + (size_t)idx * 8);
    } else {
        int idx = (b - 288) * 256 + tid;         // < 2457600 exactly
        int row = idx / 768, col = idx - row * 768;
        if (row >= 3136) { A[idx] = __float2bfloat16(0.f); return; }
        int bb = row / 196, pp = row - bb * 196;
        int gy = pp / 14, gx = pp - gy * 14;
        int c = col >> 8, rem = col & 255, py = rem >> 4, px = rem & 15;
        A[idx] = __float2bfloat16(
            x[((size_t)(bb * 3 + c) * 224 + gy * 16 + py) * 224 + gx * 16 + px]);
    }
}

// ---------------- pre-loop stage 2: patch GEMM + assemble + cls + wconv0 ------
// blocks [0,150): patch-embed GEMM 128x128 tiles, epilogue adds pb+pos and
//                 writes h/hb directly (assemble fused; tokens n>=1)
// blocks [150,166): cls rows (token 0 of each batch)
// blocks [166,4774): layer-0 wconv -> wdst (fills CUs idle during the GEMM)
__global__ __launch_bounds__(256) void patch_fused(
    const bf16* __restrict__ A, const bf16* __restrict__ Bw,
    const float* __restrict__ pb, const float* __restrict__ cls,
    const float* __restrict__ pos,
    float* __restrict__ h, bf16* __restrict__ hb,
    const float* __restrict__ wq, const float* __restrict__ wk,
    const float* __restrict__ wv, const float* __restrict__ wo,
    const float* __restrict__ wu, const float* __restrict__ wg,
    const float* __restrict__ wd, bf16* __restrict__ wdst) {
    __shared__ __align__(16) bf16 As[128 * 32];
    __shared__ __align__(16) bf16 Bs[128 * 32];
    const int bb = blockIdx.x;
    const int tid = threadIdx.x;
    if (bb >= 166) {
        int idx = (bb - 166) * 256 + tid;        // < 1179648 exactly
        wconv_body(idx, wq, wk, wv, wo, wu, wg, wd, wdst);
        return;
    }
    if (bb >= 150) {
        int bi = bb - 150;                       // batch 0..15
        size_t row = (size_t)bi * 197 * 768;
#pragma unroll
        for (int i = 0; i < 3; i++) {
            int c = tid + i * 256;
            float v = cls[c] + pos[c];
            h[row + c] = v;
            hb[row + c] = __float2bfloat16(v);
        }
        return;
    }
    const int lane = tid & 63, wave = tid >> 6;
    const int wm = wave & 1, wn = wave >> 1;
    const int quad = lane >> 4, l16 = lane & 15;
    const int nt = bb % 6;
    const int row0 = (bb / 6) * 128;
    const int col0 = nt * 128;
    const bf16* Ab = A + (size_t)row0 * 768;
    const bf16* Bb = Bw + (size_t)col0 * 768;

    f32x4 acc[4][4];
    f32x4 zero = {0.f, 0.f, 0.f, 0.f};
#pragma unroll
    for (int i = 0; i < 4; i++)
#pragma unroll
        for (int j = 0; j < 4; j++) acc[i][j] = zero;

    for (int k0 = 0; k0 < 768; k0 += 32) {
#pragma unroll
        for (int it = 0; it < 2; ++it) {
            int cidx = it * 256 + tid;
            int r = cidx >> 2, cg = cidx & 3;
            load_lds16(Ab + (size_t)r * 768 + k0 + cg * 8, As + cidx * 8);
            load_lds16(Bb + (size_t)r * 768 + k0 + cg * 8, Bs + cidx * 8);
        }
        __syncthreads();
        bf16x8 av[4], bv[4];
#pragma unroll
        for (int i = 0; i < 4; i++) {
            av[i] = *(const bf16x8*)(As + (wm * 64 + i * 16 + l16) * 32 + quad * 8);
            bv[i] = *(const bf16x8*)(Bs + (wn * 64 + i * 16 + l16) * 32 + quad * 8);
        }
#pragma unroll
        for (int i = 0; i < 4; i++)
#pragma unroll
            for (int j = 0; j < 4; j++)
                acc[i][j] = __builtin_amdgcn_mfma_f32_16x16x32_bf16(av[i], bv[j], acc[i][j], 0, 0, 0);
        __syncthreads();
    }
    // fused assemble: tproj + pb + pos -> h, hb (tokens n>=1)
#pragma unroll
    for (int i = 0; i < 4; i++) {
        int rr = row0 + wm * 64 + i * 16 + quad * 4;
#pragma unroll
        for (int j = 0; j < 4; j++) {
            int cc = col0 + wn * 64 + j * 16 + l16;
#pragma unroll
            for (int r = 0; r < 4; r++) {
                int p = rr + r;                  // patch row 0..3199
                if (p < 3136) {
                    int bi = p / 196, n = p - bi * 196;
                    float val = acc[i][j][r] + pb[cc] + pos[(size_t)(n + 1) * 768 + cc];
                    size_t hr = (size_t)(bi * 197 + n + 1) * 768 + cc;
                    h[hr] = val;
                    hb[hr] = __float2bfloat16(val);
                }
            }
        }
    }
}

// ---------------- bf16 GEMM: C = A @ W^T (m97 structure, all-bf16 staging) ----
// grid.x = nSegs*tilesPerSeg; grid.y = M/128; grid.z = split-K part
__global__ __launch_bounds__(256) void gemm_bt(
    const bf16* __restrict__ A, int lda,
    const bf16* __restrict__ B0, const bf16* __restrict__ B1, const bf16* __restrict__ B2,
    int tilesPerSeg, int segColStride,
    void* __restrict__ Cv, int ldc, long long partStride,
    int Klen, int ldb, int outBf16) {
    __shared__ __align__(16) bf16 As[128 * 32];
    __shared__ __align__(16) bf16 Bs[128 * 32];
    const int tid = threadIdx.x;
    const int lane = tid & 63, wave = tid >> 6;
    const int wm = wave & 1, wn = wave >> 1;
    const int quad = lane >> 4, l16 = lane & 15;
    const int seg = blockIdx.x / tilesPerSeg;
    const int nt = blockIdx.x - seg * tilesPerSeg;
    const bf16* B = (seg == 0) ? B0 : (seg == 1 ? B1 : B2);
    const int row0 = blockIdx.y * 128;
    const int col0 = nt * 128;
    const long long kofs = (long long)blockIdx.z * Klen;
    const bf16* Ab = A + (size_t)row0 * lda + kofs;
    const bf16* Bb = B + (size_t)col0 * ldb + kofs;
    const long long cofs = (long long)blockIdx.z * partStride + (long long)seg * segColStride;

    f32x4 acc[4][4];
    f32x4 zero = {0.f, 0.f, 0.f, 0.f};
#pragma unroll
    for (int i = 0; i < 4; i++)
#pragma unroll
        for (int j = 0; j < 4; j++) acc[i][j] = zero;

    for (int k0 = 0; k0 < Klen; k0 += 32) {
#pragma unroll
        for (int it = 0; it < 2; ++it) {
            int cidx = it * 256 + tid;
            int r = cidx >> 2, cg = cidx & 3;
            load_lds16(Ab + (size_t)r * lda + k0 + cg * 8, As + cidx * 8);
            load_lds16(Bb + (size_t)r * ldb + k0 + cg * 8, Bs + cidx * 8);
        }
        __syncthreads();
        bf16x8 av[4], bv[4];
#pragma unroll
        for (int i = 0; i < 4; i++) {
            av[i] = *(const bf16x8*)(As + (wm * 64 + i * 16 + l16) * 32 + quad * 8);
            bv[i] = *(const bf16x8*)(Bs + (wn * 64 + i * 16 + l16) * 32 + quad * 8);
        }
#pragma unroll
        for (int i = 0; i < 4; i++)
#pragma unroll
            for (int j = 0; j < 4; j++)
                acc[i][j] = __builtin_amdgcn_mfma_f32_16x16x32_bf16(av[i], bv[j], acc[i][j], 0, 0, 0);
        __syncthreads();
    }
    if (outBf16) {
        bf16* Cb = (bf16*)Cv + cofs;
#pragma unroll
        for (int i = 0; i < 4; i++) {
            int rr = row0 + wm * 64 + i * 16 + quad * 4;
#pragma unroll
            for (int j = 0; j < 4; j++) {
                int cc = col0 + wn * 64 + j * 16 + l16;
#pragma unroll
                for (int r = 0; r < 4; r++)
                    Cb[(size_t)(rr + r) * ldc + cc] = __float2bfloat16(acc[i][j][r]);
            }
        }
    } else {
        float* Cb = (float*)Cv + cofs;
#pragma unroll
        for (int i = 0; i < 4; i++) {
            int rr = row0 + wm * 64 + i * 16 + quad * 4;
#pragma unroll
            for (int j = 0; j < 4; j++) {
                int cc = col0 + wn * 64 + j * 16 + l16;
#pragma unroll
                for (int r = 0; r < 4; r++)
                    Cb[(size_t)(rr + r) * ldc + cc] = acc[i][j][r];
            }
        }
    }
}

// ---------------- fused QKV GEMM + q/k cosine-norm + next-layer wconv ---------
// blocks [0,450): QKV GEMM (seg = b/150 in {q,k,v}; rem = b%150: nt = rem%6,
//                 ry = rem/6). Each wave's 64-col span is one complete head.
// blocks [450,5058): f32->bf16 conversion of layer l+1 weights -> wdst
__global__ __launch_bounds__(256) void gemm_qkv(
    const bf16* __restrict__ A,
    const bf16* __restrict__ Bq, const bf16* __restrict__ Bk, const bf16* __restrict__ Bv,
    const float* __restrict__ s_l,
    bf16* __restrict__ Qd, bf16* __restrict__ Kd, bf16* __restrict__ VTd,
    const float* __restrict__ wq, const float* __restrict__ wk,
    const float* __restrict__ wv, const float* __restrict__ wo,
    const float* __restrict__ wu, const float* __restrict__ wg,
    const float* __restrict__ wd, bf16* __restrict__ wdst) {
    __shared__ __align__(16) bf16 As[128 * 32];
    __shared__ __align__(16) bf16 Bs[128 * 32];
    const int bb = blockIdx.x;
    const int tid = threadIdx.x;
    if (bb >= 450) {
        int idx = (bb - 450) * 256 + tid;        // < 1179648 exactly
        wconv_body(idx, wq, wk, wv, wo, wu, wg, wd, wdst);
        return;
    }
    const int lane = tid & 63, wave = tid >> 6;
    const int wm = wave & 1, wn = wave >> 1;
    const int quad = lane >> 4, l16 = lane & 15;
    const int seg = bb / 150;
    const int rem = bb - seg * 150;
    const int nt = rem % 6;
    const int row0 = (rem / 6) * 128;
    const int col0 = nt * 128;
    const bf16* B = (seg == 0) ? Bq : (seg == 1 ? Bk : Bv);
    const bf16* Ab = A + (size_t)row0 * 768;
    const bf16* Bb = B + (size_t)col0 * 768;

    f32x4 acc[4][4];
    f32x4 zero = {0.f, 0.f, 0.f, 0.f};
#pragma unroll
    for (int i = 0; i < 4; i++)
#pragma unroll
        for (int j = 0; j < 4; j++) acc[i][j] = zero;

    for (int k0 = 0; k0 < 768; k0 += 32) {
#pragma unroll
        for (int it = 0; it < 2; ++it) {
            int cidx = it * 256 + tid;
            int r = cidx >> 2, cg = cidx & 3;
            load_lds16(Ab + (size_t)r * 768 + k0 + cg * 8, As + cidx * 8);
            load_lds16(Bb + (size_t)r * 768 + k0 + cg * 8, Bs + cidx * 8);
        }
        __syncthreads();
        bf16x8 av[4], bv[4];
#pragma unroll
        for (int i = 0; i < 4; i++) {
            av[i] = *(const bf16x8*)(As + (wm * 64 + i * 16 + l16) * 32 + quad * 8);
            bv[i] = *(const bf16x8*)(Bs + (wn * 64 + i * 16 + l16) * 32 + quad * 8);
        }
#pragma unroll
        for (int i = 0; i < 4; i++)
#pragma unroll
            for (int j = 0; j < 4; j++)
                acc[i][j] = __builtin_amdgcn_mfma_f32_16x16x32_bf16(av[i], bv[j], acc[i][j], 0, 0, 0);
        __syncthreads();
    }

    const int hcol = nt * 2 + wn;               // complete head owned by this wave
    if (seg < 2) {
        bf16* Dst = (seg == 0) ? Qd : Kd;
        float sv0[4];
#pragma unroll
        for (int j = 0; j < 4; j++) sv0[j] = s_l[hcol * 64 + j * 16 + l16] * SQRT_E;
#pragma unroll
        for (int i = 0; i < 4; i++) {
#pragma unroll
            for (int r = 0; r < 4; r++) {
                float ss = acc[i][0][r] * acc[i][0][r] + acc[i][1][r] * acc[i][1][r]
                         + acc[i][2][r] * acc[i][2][r] + acc[i][3][r] * acc[i][3][r];
#pragma unroll
                for (int m = 1; m < 16; m <<= 1) ss += __shfl_xor(ss, m);
                float inv = 1.f / fmaxf(sqrtf(ss), 1e-6f);
                int t = row0 + wm * 64 + i * 16 + quad * 4 + r;
                if (t < 3152) {
                    int b = t / 197, n = t - b * 197;
                    size_t base = ((size_t)(b * 12 + hcol) * 208 + n) * 64;
#pragma unroll
                    for (int j = 0; j < 4; j++)
                        Dst[base + j * 16 + l16] =
                            __float2bfloat16(acc[i][j][r] * inv * sv0[j]);
                }
            }
        }
    } else {
#pragma unroll
        for (int i = 0; i < 4; i++) {
#pragma unroll
            for (int r = 0; r < 4; r++) {
                int t = row0 + wm * 64 + i * 16 + quad * 4 + r;
                if (t < 3152) {
                    int b = t / 197, n = t - b * 197;
                    size_t vbase = (size_t)(b * 12 + hcol) * 64 * 224 + n;
#pragma unroll
                    for (int j = 0; j < 4; j++)
                        VTd[vbase + (size_t)(j * 16 + l16) * 224] =
                            __float2bfloat16(acc[i][j][r]);
                }
            }
        }
    }
}

// ---------------- fused up/gate GEMM + SwiGLU -> hidden bf16 ------------------
__global__ __launch_bounds__(256) void gemm_upgate(
    const bf16* __restrict__ A, const bf16* __restrict__ Bu, const bf16* __restrict__ Bv,
    const float* __restrict__ su, const float* __restrict__ sv,
    bf16* __restrict__ H) {
    __shared__ __align__(16) bf16 As[128 * 32];
    __shared__ __align__(16) bf16 Bus[64 * 32];
    __shared__ __align__(16) bf16 Bvs[64 * 32];
    const int tid = threadIdx.x;
    const int lane = tid & 63, wave = tid >> 6;
    const int wm = wave & 1, wn = wave >> 1;     // wn in 0..1 -> 32-col half
    const int quad = lane >> 4, l16 = lane & 15;
    const int ct = blockIdx.x;                   // 0..47
    const int row0 = blockIdx.y * 128;
    const bf16* Ab = A + (size_t)row0 * 768;
    const bf16* Bub = Bu + (size_t)ct * 64 * 768;
    const bf16* Bvb = Bv + (size_t)ct * 64 * 768;

    f32x4 au[4][2], av_[4][2];
    f32x4 zero = {0.f, 0.f, 0.f, 0.f};
#pragma unroll
    for (int i = 0; i < 4; i++)
#pragma unroll
        for (int j = 0; j < 2; j++) { au[i][j] = zero; av_[i][j] = zero; }

    for (int k0 = 0; k0 < 768; k0 += 32) {
#pragma unroll
        for (int it = 0; it < 2; ++it) {
            int cidx = it * 256 + tid;
            int r = cidx >> 2, cg = cidx & 3;
            load_lds16(Ab + (size_t)r * 768 + k0 + cg * 8, As + cidx * 8);
        }
        {
            int r = tid >> 2, cg = tid & 3;
            load_lds16(Bub + (size_t)r * 768 + k0 + cg * 8, Bus + tid * 8);
            load_lds16(Bvb + (size_t)r * 768 + k0 + cg * 8, Bvs + tid * 8);
        }
        __syncthreads();
        bf16x8 a[4], bu[2], bv[2];
#pragma unroll
        for (int i = 0; i < 4; i++)
            a[i] = *(const bf16x8*)(As + (wm * 64 + i * 16 + l16) * 32 + quad * 8);
#pragma unroll
        for (int j = 0; j < 2; j++) {
            bu[j] = *(const bf16x8*)(Bus + (wn * 32 + j * 16 + l16) * 32 + quad * 8);
            bv[j] = *(const bf16x8*)(Bvs + (wn * 32 + j * 16 + l16) * 32 + quad * 8);
        }
#pragma unroll
        for (int i = 0; i < 4; i++)
#pragma unroll
            for (int j = 0; j < 2; j++) {
                au[i][j]  = __builtin_amdgcn_mfma_f32_16x16x32_bf16(a[i], bu[j], au[i][j], 0, 0, 0);
                av_[i][j] = __builtin_amdgcn_mfma_f32_16x16x32_bf16(a[i], bv[j], av_[i][j], 0, 0, 0);
            }
        __syncthreads();
    }
#pragma unroll
    for (int j = 0; j < 2; j++) {
        int cc = ct * 64 + wn * 32 + j * 16 + l16;
        float suc = su[cc];
        float svc = sv[cc] * SQRT_E;
#pragma unroll
        for (int i = 0; i < 4; i++) {
            int rr = row0 + wm * 64 + i * 16 + quad * 4;
#pragma unroll
            for (int r = 0; r < 4; r++) {
                float u = au[i][j][r] * suc;
                float v = av_[i][j][r] * svc;
                float sig = 1.f / (1.f + __expf(-v));
                H[(size_t)(rr + r) * 3072 + cc] = __float2bfloat16(u * v * sig);
            }
        }
    }
}

// ---------------- attention: one wave per (b,h,q-tile) ------------------------
// No-max softmax: q,k are cosine-normalized and scaled by s*sqrt(E)=1, so
// |logit*8| <= 8 -> exp in [e-8, e8], overflow-free in f32. 1/sum folded
// into the PV epilogue (P stored unnormalized in LDS).
__global__ __launch_bounds__(64) void attn_kernel(
    const bf16* __restrict__ Q, const bf16* __restrict__ K,
    const bf16* __restrict__ VT, bf16* __restrict__ O) {
    __shared__ __align__(16) bf16 Ps[16 * 224];
    int lane = threadIdx.x;
    int quad = lane >> 4, l16 = lane & 15;
    int bh = blockIdx.x % 192;
    int qt = blockIdx.x / 192;
    int b = bh / 12, h = bh - b * 12;
    const bf16* Qb = Q + (size_t)bh * 208 * 64;
    const bf16* Kb = K + (size_t)bh * 208 * 64;
    const bf16* Vb = VT + (size_t)bh * 64 * 224;
    f32x4 zero = {0.f, 0.f, 0.f, 0.f};

    bf16x8 a0 = *(const bf16x8*)(Qb + (qt * 16 + l16) * 64 + quad * 8);
    bf16x8 a1 = *(const bf16x8*)(Qb + (qt * 16 + l16) * 64 + quad * 8 + 32);

    f32x4 lg[13];
#pragma unroll
    for (int kt = 0; kt < 13; kt++) {
        bf16x8 b0 = *(const bf16x8*)(Kb + (kt * 16 + l16) * 64 + quad * 8);
        bf16x8 b1 = *(const bf16x8*)(Kb + (kt * 16 + l16) * 64 + quad * 8 + 32);
        f32x4 c = zero;
        c = __builtin_amdgcn_mfma_f32_16x16x32_bf16(a0, b0, c, 0, 0, 0);
        c = __builtin_amdgcn_mfma_f32_16x16x32_bf16(a1, b1, c, 0, 0, 0);
        lg[kt] = c;
    }
    float sm[4] = {0.f, 0.f, 0.f, 0.f};
#pragma unroll
    for (int kt = 0; kt < 13; kt++) {
        bool valid = (kt * 16 + l16) < 197;
#pragma unroll
        for (int r = 0; r < 4; r++) {
            float p = valid ? __expf(lg[kt][r] * 8.0f) : 0.f;
            lg[kt][r] = p;
            sm[r] += p;
        }
    }
#pragma unroll
    for (int m = 1; m < 16; m <<= 1)
#pragma unroll
        for (int r = 0; r < 4; r++) sm[r] += __shfl_xor(sm[r], m);
    float inv[4];
#pragma unroll
    for (int r = 0; r < 4; r++) inv[r] = 1.f / sm[r];
#pragma unroll
    for (int kt = 0; kt < 13; kt++)
#pragma unroll
        for (int r = 0; r < 4; r++)
            Ps[(quad * 4 + r) * 224 + kt * 16 + l16] = __float2bfloat16(lg[kt][r]);
#pragma unroll
    for (int r = 0; r < 4; r++)
        Ps[(quad * 4 + r) * 224 + 208 + l16] = __float2bfloat16(0.f);
    __syncthreads();
#pragma unroll
    for (int nt = 0; nt < 4; nt++) {
        f32x4 o = zero;
#pragma unroll
        for (int ks = 0; ks < 7; ks++) {
            bf16x8 pa = *(const bf16x8*)(Ps + l16 * 224 + ks * 32 + quad * 8);
            bf16x8 vb = *(const bf16x8*)(Vb + (nt * 16 + l16) * 224 + ks * 32 + quad * 8);
            o = __builtin_amdgcn_mfma_f32_16x16x32_bf16(pa, vb, o, 0, 0, 0);
        }
#pragma unroll
        for (int r = 0; r < 4; r++) {
            int tok = qt * 16 + quad * 4 + r;
            if (tok < 197)
                O[(size_t)(b * 197 + tok) * 768 + h * 64 + nt * 16 + l16] =
                    __float2bfloat16(o[r] * inv[r]);
        }
    }
}

// ---------------- residual + cosine norms (bf16 split-K partials) -------------
// f32 residual stream (h). Optional fused output layernorm: after cosine norm,
// sum(v^2)=1 exactly, so var = 1/768 - mean^2 -> one extra block_sum.
__global__ __launch_bounds__(256) void residual_cos(
    const bf16* __restrict__ proj, int nParts, long long partStride,
    const float* __restrict__ alpha,
    float* __restrict__ h, bf16* __restrict__ hb,
    const float* __restrict__ fcw, const float* __restrict__ fcb,
    float* __restrict__ lnout) {
    __shared__ float sbuf[4];
    int row = blockIdx.x, tid = threadIdx.x;
    float p[3];
    float ss = 0.f;
#pragma unroll
    for (int i = 0; i < 3; i++) {
        int c = tid + i * 256;
        float v = 0.f;
        for (int pt = 0; pt < nParts; pt++)
            v += __bfloat162float(proj[(long long)pt * partStride + (size_t)row * 768 + c]);
        p[i] = v;
        ss += v * v;
    }
    ss = block_sum(ss, sbuf);
    float inv1 = 1.f / fmaxf(sqrtf(ss), 1e-6f);
    float ss2 = 0.f;
#pragma unroll
    for (int i = 0; i < 3; i++) {
        int c = tid + i * 256;
        float hv = h[(size_t)row * 768 + c];
        float a = alpha[c] * ASCALE;
        float m = hv + a * (p[i] * inv1 - hv);
        p[i] = m;
        ss2 += m * m;
    }
    ss2 = block_sum(ss2, sbuf);
    float inv2 = 1.f / fmaxf(sqrtf(ss2), 1e-6f);
    float v0 = p[0] * inv2, v1 = p[1] * inv2, v2 = p[2] * inv2;
    {
        int c = tid;
        h[(size_t)row * 768 + c] = v0;
        hb[(size_t)row * 768 + c] = __float2bfloat16(v0);
        h[(size_t)row * 768 + c + 256] = v1;
        hb[(size_t)row * 768 + c + 256] = __float2bfloat16(v1);
        h[(size_t)row * 768 + c + 512] = v2;
        hb[(size_t)row * 768 + c + 512] = __float2bfloat16(v2);
    }
    if (lnout) {
        float s = block_sum(v0 + v1 + v2, sbuf);
        float mean = s * (1.f / 768.f);
        float var = (1.f / 768.f) - mean * mean;
        float invs = 1.f / sqrtf(var + 1e-6f);
        int b = row / 197, n = row - b * 197;
        if (n >= 1) {
            size_t obase = (size_t)(b * 196 + n - 1) * 768;
            lnout[obase + tid]       = (v0 - mean) * invs * fcw[tid] + fcb[tid];
            lnout[obase + tid + 256] = (v1 - mean) * invs * fcw[tid + 256] + fcb[tid + 256];
            lnout[obase + tid + 512] = (v2 - mean) * invs * fcw[tid + 512] + fcb[tid + 512];
        }
    }
}

extern "C" void kernel_launch(void* const* d_in, const int* in_sizes, int n_in,
                              void* d_out, int out_size, void* d_ws, size_t ws_size,
                              hipStream_t stream) {
    (void)in_sizes; (void)n_in; (void)out_size; (void)ws_size;
    const float* x      = (const float*)d_in[0];
    const float* patchw = (const float*)d_in[1];
    const float* patchb = (const float*)d_in[2];
    const float* cls    = (const float*)d_in[3];
    const float* pos    = (const float*)d_in[4];
    const float* Wq     = (const float*)d_in[5];
    const float* Wk     = (const float*)d_in[6];
    const float* Wv     = (const float*)d_in[7];
    const float* Wo     = (const float*)d_in[8];
    const float* s_qk   = (const float*)d_in[9];
    const float* Wup    = (const float*)d_in[10];
    const float* Wgate  = (const float*)d_in[11];
    const float* Wdown  = (const float*)d_in[12];
    const float* s_u    = (const float*)d_in[13];
    const float* s_v    = (const float*)d_in[14];
    const float* alA    = (const float*)d_in[15];
    const float* alM    = (const float*)d_in[16];
    const float* fcw    = (const float*)d_in[17];
    const float* fcb    = (const float*)d_in[18];
    float* out = (float*)d_out;

    char* ws = (char*)d_ws;
    size_t ofs = 0;
    auto alloc = [&](size_t bytes) -> void* {
        void* p = ws + ofs;
        ofs += (bytes + 255) & ~(size_t)255;
        return p;
    };
    float* h      = (float*)alloc((size_t)MPAD * 768 * 4);        //  9.8 MB (f32 residual)
    float* part   = (float*)alloc((size_t)4 * MPAD * 768 * 4);    // 39.3 MB: bf16 partials | f32 tproj
    bf16*  hb     = (bf16*)alloc((size_t)MPAD * 768 * 2);         //  4.9 MB
    bf16*  attno  = (bf16*)alloc((size_t)MPAD * 768 * 2);         //  4.9 MB
    bf16*  hidden = (bf16*)alloc((size_t)MPAD * 3072 * 2);        // 19.7 MB (also Apatch)
    size_t qkvt_bytes = ((size_t)192 * 208 * 64 * 2) * 2 + (size_t)192 * 64 * 224 * 2;
    bf16*  Qb     = (bf16*)alloc(qkvt_bytes);                     // 15.7 MB
    bf16*  Kb     = Qb + (size_t)192 * 208 * 64;
    bf16*  VTb    = Kb + (size_t)192 * 208 * 64;
    const size_t WPL = 9437184;                                   // bf16 elems per layer
    bf16*  wbf0   = (bf16*)alloc(WPL * 2);                        // 18.9 MB (even layers)
    bf16*  wbf1   = (bf16*)alloc(WPL * 2);                        // 18.9 MB (odd layers)
    bf16*  pwb    = (bf16*)alloc((size_t)589824 * 2);             //  1.2 MB patch weights

    bf16*  partb  = (bf16*)part;                 // in-loop bf16 split-K partials
    bf16*  Apatch = hidden;

    const long long PSTR = (long long)MPAD * 768;
    const size_t EE = 768 * 768, FE = (size_t)3072 * 768;

    // ---- pre-loop: im2col/patchw cvt, then GEMM+assemble+cls+wconv0 fused ----
    prep_kernel<<<9888, 256, 0, stream>>>(x, Apatch, patchw, pwb);
    patch_fused<<<4774, 256, 0, stream>>>(Apatch, pwb, patchb, cls, pos, h, hb,
                                          Wq, Wk, Wv, Wo, Wup, Wgate, Wdown, wbf0);
    // zero Q/K/VT pads once per call (epilogues write only real tokens)
    hipMemsetAsync(Qb, 0, qkvt_bytes, stream);

    for (int l = 0; l < 12; l++) {
        bf16* wl    = (l & 1) ? wbf1 : wbf0;
        bf16* wnext = (l & 1) ? wbf0 : wbf1;
        bf16* wqb = wl;
        bf16* wkb = wl + 589824;
        bf16* wvb = wl + 1179648;
        bf16* wob = wl + 1769472;
        bf16* wub = wl + 2359296;
        bf16* wgb = wl + 4718592;
        bf16* wdb = wl + 7077888;
        int ln = (l < 11) ? (l + 1) : l;         // next-layer weights (unused at l=11)

        // fused QKV GEMM + q/k cosine-norm + overlapped next-layer wconv
        gemm_qkv<<<(l < 11) ? 5058 : 450, 256, 0, stream>>>(
            hb, wqb, wkb, wvb, s_qk + (size_t)l * 768, Qb, Kb, VTb,
            Wq + (size_t)ln * EE, Wk + (size_t)ln * EE,
            Wv + (size_t)ln * EE, Wo + (size_t)ln * EE,
            Wup + (size_t)ln * FE, Wgate + (size_t)ln * FE,
            Wdown + (size_t)ln * FE, wnext);
        attn_kernel<<<2496, 64, 0, stream>>>(Qb, Kb, VTb, attno);
        // O-proj split-K=3 GEMM, bf16 partials (8 K-steps/block, 450 blocks)
        gemm_bt<<<dim3(6, 25, 3), 256, 0, stream>>>(attno, 768, wob, wob, wob,
                                                    6, 0, partb, 768, PSTR, 256, 768, 1);
        residual_cos<<<3152, 256, 0, stream>>>(partb, 3, PSTR, alA + (size_t)l * 768,
                                               h, hb, fcw, fcb, (float*)nullptr);
        // fused up/gate + SwiGLU -> hidden bf16
        gemm_upgate<<<dim3(48, 25), 256, 0, stream>>>(hb, wub, wgb,
                                                      s_u + (size_t)l * 3072,
                                                      s_v + (size_t)l * 3072, hidden);
        // down, split-K = 4, bf16 partials
        gemm_bt<<<dim3(6, 25, 4), 256, 0, stream>>>(hidden, 3072, wdb, wdb, wdb,
                                                    6, 0, partb, 768, PSTR, 768, 3072, 1);
        float* lnp = (l == 10) ? out : (l == 11) ? (out + 2408448) : (float*)nullptr;
        residual_cos<<<3152, 256, 0, stream>>>(partb, 4, PSTR, alM + (size_t)l * 768,
                                               h, hb, fcw, fcb, lnp);
    }
}